// Round 1
// baseline (1189.870 us; speedup 1.0000x reference)
//
#include <hip/hip_runtime.h>
#include <stdint.h>

// QuantizedLinear: y = x @ quantdequant(w).T + bias
// M=8192, N=4096, K=4096 (derived at launch from in_sizes)
//
// Scheme: w -> q (int4 values stored as EXACT bf16) + scale[g][n] (fp32).
//         x -> xh + xl bf16 split during LDS staging.
//         pacc = sum_{k in group} q*(xh+xl)  (2 MFMAs / 32-K-chunk, fp32 acc)
//         acc += scale[n,g] * pacc per 128-group  (scale uniform per lane: col=lane&15)
// => ~1e-5 relative error vs fp32 reference at bf16-MFMA speed (2x work).

#define BM 128
#define BN 128
#define BK 64
#define GS 128

typedef float    f32x4 __attribute__((ext_vector_type(4)));
typedef uint32_t u32x4 __attribute__((ext_vector_type(4)));
typedef uint32_t u32x2 __attribute__((ext_vector_type(2)));

__device__ __forceinline__ uint16_t f2bf(float f) {
  uint32_t u = __float_as_uint(f);
  uint32_t r = u + 0x7FFFu + ((u >> 16) & 1u);   // RNE, inputs finite
  return (uint16_t)(r >> 16);
}
__device__ __forceinline__ float bf2f(uint16_t h) {
  return __uint_as_float((uint32_t)h << 16);
}

__device__ __forceinline__ void gload_lds16(const void* g, void* l) {
  __builtin_amdgcn_global_load_lds(
      (const __attribute__((address_space(1))) void*)g,
      (__attribute__((address_space(3))) void*)l, 16, 0, 0);
}

// inline-asm MFMA: type-agnostic operands (robust across builtin signature variants)
__device__ __forceinline__ void mfma16x16x32bf16(f32x4& d, const u32x4& a, const u32x4& b) {
  asm("v_mfma_f32_16x16x32_bf16 %0, %1, %2, %0" : "+v"(d) : "v"(a), "v"(b));
}

// ---------------- preprocess: group-wise int4 fake-quant of w -----------------
// one wave per (n, group): q stored bf16 [N][K], scale fp32 [G][N]
__global__ void quant_pre(const float* __restrict__ w, uint16_t* __restrict__ q,
                          float* __restrict__ scales, int N, int K) {
  int wavesPerBlock = blockDim.x >> 6;
  int gwave = blockIdx.x * wavesPerBlock + ((int)threadIdx.x >> 6);
  int lane = threadIdx.x & 63;
  int gpr = K / GS;                       // groups per row
  int n = gwave / gpr;
  int g = gwave % gpr;
  if (n >= N) return;
  const float* wp = w + (size_t)n * K + (size_t)g * GS;
  float2 v = *reinterpret_cast<const float2*>(wp + lane * 2);
  float a = fmaxf(fabsf(v.x), fabsf(v.y));
#pragma unroll
  for (int off = 32; off > 0; off >>= 1) a = fmaxf(a, __shfl_xor(a, off));
  float scale = a / 7.0f;                 // absmax / QMAX (true divide, matches ref)
  float ss = (scale > 0.0f) ? scale : 1.0f;
  float q0 = fminf(fmaxf(rintf(v.x / ss), -8.0f), 7.0f);   // rintf = RNE = jnp.round
  float q1 = fminf(fmaxf(rintf(v.y / ss), -8.0f), 7.0f);
  uint32_t packed = (uint32_t)f2bf(q0) | ((uint32_t)f2bf(q1) << 16);
  *reinterpret_cast<uint32_t*>(q + (size_t)n * K + (size_t)g * GS + lane * 2) = packed;
  if (lane == 0) scales[(size_t)g * N + n] = scale;
}

// ------------------------------- GEMM ----------------------------------------
// 128x128 tile, BK=64, 4 waves (2x2), each wave 64x64 via 4x4 frags of 16x16x32.
// A (x): reg-staged fp32 -> hi/lo bf16, XOR-swizzled ds_write. single-buffered.
// B (q): global_load_lds dwordx4, pre-swizzled global source, linear LDS dest,
//        swizzled read (involution: slot ^= row&7). double-buffered.
__global__ __launch_bounds__(256, 2) void qgemm(
    const float* __restrict__ x, const uint16_t* __restrict__ q,
    const float* __restrict__ scales, const float* __restrict__ bias,
    float* __restrict__ out, int M, int N, int K) {
  __shared__ uint16_t sAh[BM * BK];       // 16 KB
  __shared__ uint16_t sAl[BM * BK];       // 16 KB
  __shared__ uint16_t sB[2][BN * BK];     // 32 KB  (total 64 KB -> 2 blocks/CU)

  const int tid = threadIdx.x;
  const int lane = tid & 63;
  const int wid = tid >> 6;
  const int wm = wid >> 1;                // wave row   (0..1)
  const int wn = wid & 1;                 // wave col   (0..1)

  // XCD-aware bijective swizzle (grid % 8 == 0 here)
  int nblkTotal = N / BN;
  int bid = (int)blockIdx.x;
  int nwg = (int)gridDim.x;
  int id = bid;
  if ((nwg & 7) == 0) { int cpx = nwg >> 3; id = (bid & 7) * cpx + (bid >> 3); }
  const int mbase = (id / nblkTotal) * BM;
  const int nbase = (id % nblkTotal) * BN;
  const int nt = K / BK;

  f32x4 acc[4][4] = {};
  f32x4 pacc[4][4] = {};
  float sreg[4];
  float4 areg[8];

  auto loadA = [&](int t) {
#pragma unroll
    for (int p = 0; p < 8; ++p) {
      int idx = p * 256 + tid;
      int row = idx >> 4;
      int f4 = idx & 15;
      areg[p] = *reinterpret_cast<const float4*>(
          x + (size_t)(mbase + row) * K + (size_t)t * BK + f4 * 4);
    }
  };

  auto writeA = [&]() {
#pragma unroll
    for (int p = 0; p < 8; ++p) {
      int idx = p * 256 + tid;
      int row = idx >> 4;
      int f4 = idx & 15;
      int boff = row * 128 + (((f4 >> 1) ^ (row & 7)) << 4) + ((f4 & 1) << 3);
      float fx[4] = {areg[p].x, areg[p].y, areg[p].z, areg[p].w};
      uint16_t h[4], l[4];
#pragma unroll
      for (int e = 0; e < 4; ++e) {
        h[e] = f2bf(fx[e]);
        l[e] = f2bf(fx[e] - bf2f(h[e]));
      }
      u32x2 hv = { (uint32_t)h[0] | ((uint32_t)h[1] << 16),
                   (uint32_t)h[2] | ((uint32_t)h[3] << 16) };
      u32x2 lv = { (uint32_t)l[0] | ((uint32_t)l[1] << 16),
                   (uint32_t)l[2] | ((uint32_t)l[3] << 16) };
      *reinterpret_cast<u32x2*>(reinterpret_cast<char*>(sAh) + boff) = hv;
      *reinterpret_cast<u32x2*>(reinterpret_cast<char*>(sAl) + boff) = lv;
    }
  };

  auto issueB = [&](int t, int buf) {
#pragma unroll
    for (int i = 0; i < 4; ++i) {
      int gran = i * 256 + wid * 64 + lane;           // 16B granule index
      int row = gran >> 3;
      int slot = gran & 7;
      const uint16_t* src = q + (size_t)(nbase + row) * K + (size_t)t * BK
                              + ((slot ^ (row & 7)) << 3);
      uint16_t* dst = &sB[buf][(size_t)(i * 256 + wid * 64) * 8]; // wave-uniform base
      gload_lds16(src, dst);
    }
  };

  auto computeTile = [&](int buf) {
#pragma unroll
    for (int kk = 0; kk < 2; ++kk) {
      u32x4 ah[4], al[4], bf[4];
#pragma unroll
      for (int i = 0; i < 4; ++i) {
        int row = wm * 64 + i * 16 + (lane & 15);
        int slot = kk * 4 + (lane >> 4);
        int boff = row * 128 + ((slot ^ (row & 7)) << 4);
        ah[i] = *reinterpret_cast<const u32x4*>(reinterpret_cast<const char*>(sAh) + boff);
        al[i] = *reinterpret_cast<const u32x4*>(reinterpret_cast<const char*>(sAl) + boff);
      }
#pragma unroll
      for (int j = 0; j < 4; ++j) {
        int row = wn * 64 + j * 16 + (lane & 15);
        int slot = kk * 4 + (lane >> 4);
        int boff = row * 128 + ((slot ^ (row & 7)) << 4);
        bf[j] = *reinterpret_cast<const u32x4*>(reinterpret_cast<const char*>(sB[buf]) + boff);
      }
#pragma unroll
      for (int i = 0; i < 4; ++i)
#pragma unroll
        for (int j = 0; j < 4; ++j) {
          mfma16x16x32bf16(pacc[i][j], ah[i], bf[j]);
          mfma16x16x32bf16(pacc[i][j], al[i], bf[j]);
        }
    }
  };

  // prologue
  loadA(0);
  issueB(0, 0);
  writeA();
  __syncthreads();           // implicit vmcnt drain covers B(0) gload_lds

  int cur = 0;
  for (int t = 0; t < nt; ++t) {
    if (t + 1 < nt) {
      issueB(t + 1, cur ^ 1);   // overlaps compute; drained at barrier after compute
      loadA(t + 1);
    }
    if ((t & 1) == 0) {
      int g = t >> 1;
#pragma unroll
      for (int j = 0; j < 4; ++j)
        sreg[j] = scales[(size_t)g * N + nbase + wn * 64 + j * 16 + (lane & 15)];
    }
    computeTile(cur);
    if (t & 1) {               // end of 128-group: fold scale into master acc
#pragma unroll
      for (int j = 0; j < 4; ++j) {
        float s = sreg[j];
#pragma unroll
        for (int i = 0; i < 4; ++i) {
#pragma unroll
          for (int r = 0; r < 4; ++r) acc[i][j][r] += s * pacc[i][j][r];
          pacc[i][j] = (f32x4){0.f, 0.f, 0.f, 0.f};
        }
      }
    }
    __syncthreads();           // A(t) reads done; B(t+1)/areg drained (overlapped)
    if (t + 1 < nt) writeA();  // stage A(t+1) into single A buffer
    __syncthreads();
    cur ^= 1;
  }

  // epilogue: + bias, fp32 store. C/D: col = lane&15, row = (lane>>4)*4 + r
#pragma unroll
  for (int j = 0; j < 4; ++j) {
    int n = nbase + wn * 64 + j * 16 + (lane & 15);
    float b = bias[n];
#pragma unroll
    for (int i = 0; i < 4; ++i) {
      int m0 = mbase + wm * 64 + i * 16 + ((lane >> 4) << 2);
#pragma unroll
      for (int r = 0; r < 4; ++r)
        out[(size_t)(m0 + r) * N + n] = acc[i][j][r] + b;
    }
  }
}

extern "C" void kernel_launch(void* const* d_in, const int* in_sizes, int n_in,
                              void* d_out, int out_size, void* d_ws, size_t ws_size,
                              hipStream_t stream) {
  const float* x = (const float*)d_in[0];
  const float* w = (const float*)d_in[1];
  const float* bias = (const float*)d_in[2];
  float* out = (float*)d_out;

  int N = in_sizes[2];                 // 4096
  int K = in_sizes[1] / N;             // 4096
  int M = in_sizes[0] / K;             // 8192

  uint16_t* q = (uint16_t*)d_ws;                                   // N*K bf16 = 32 MiB
  float* scales = (float*)((char*)d_ws + (size_t)N * K * sizeof(uint16_t)); // G*N fp32

  int G = K / GS;
  int totalWaves = N * G;
  int preBlocks = (totalWaves + 3) / 4;  // 4 waves per 256-thread block
  quant_pre<<<preBlocks, 256, 0, stream>>>(w, q, scales, N, K);

  dim3 grid((M / BM) * (N / BN));
  qgemm<<<grid, 256, 0, stream>>>(x, q, scales, bias, out, M, N, K);
}